// Round 1
// baseline (187.935 us; speedup 1.0000x reference)
//
#include <hip/hip_runtime.h>

// PairwiseMamba: 2304 independent mamba scans (T=1024, d_inner=4, d_state=8).
// One wave = 2 sequences. Per 32-step chunk: all 64 lanes do pointwise
// featureization (lane<->t), stage (a,b,q) to LDS, then all 64 lanes do the
// linear scan (lane<->(d,s) state element). feat accumulates per-lane with no
// per-step cross-lane traffic; one butterfly reduce at the end.

#define TT 1024
#define TC 32
#define NCHUNK (TT / TC)
#define NUM_PAIRS 36
#define NSEQ 2304

__device__ __forceinline__ float fast_sigmoid(float v) {
    return __builtin_amdgcn_rcpf(1.0f + __expf(-v));
}

__global__ __launch_bounds__(64)
void pm_kernel(const float* __restrict__ raw,        // (N,2,T)
               const float* __restrict__ in_proj_w,  // (8,2)
               const float* __restrict__ conv_w,     // (4,2)
               const float* __restrict__ conv_b,     // (4)
               const float* __restrict__ x_proj_w,   // (17,4)
               const float* __restrict__ dt_proj_w,  // (4,1)
               const float* __restrict__ dt_proj_b,  // (4)
               const float* __restrict__ A_log,      // (4,8)
               const float* __restrict__ D_skip,     // (4)
               const float* __restrict__ out_proj_w, // (2,4)
               const float* __restrict__ proj_w,     // (16,2)
               const float* __restrict__ proj_b,     // (16)
               float* __restrict__ out)              // (64,16), pre-zeroed
{
    // per-half staging: ab[t][ds] (float2, row stride 33) and q[t][ds]
    __shared__ float2 s_ab[2 * (TC * 33) + 4];
    __shared__ float  s_q [2 * (TC * 33) + 4];

    const int lane = threadIdx.x;
    const int half = lane >> 5;   // which of the 2 sequences this wave owns
    const int lh   = lane & 31;   // pointwise: t-within-chunk; scan: ds = d*8+s
    const int n    = blockIdx.x * 2 + half;
    const float* rp = raw + (size_t)n * (2 * TT);

    const int abBase = half * (TC * 33 + 2);  // stagger halves across banks
    const int qBase  = half * (TC * 33 + 1);

    // ---- weights (uniform loads -> SGPRs where possible) ----
    float ipw[8][2];
#pragma unroll
    for (int j = 0; j < 8; ++j) { ipw[j][0] = in_proj_w[2*j]; ipw[j][1] = in_proj_w[2*j+1]; }
    float cw0[4], cw1[4], cbv[4], dpw[4], dpb[4], Dsk[4], ow0[4], ow1[4];
#pragma unroll
    for (int d = 0; d < 4; ++d) {
        cw0[d] = conv_w[2*d]; cw1[d] = conv_w[2*d+1]; cbv[d] = conv_b[d];
        dpw[d] = dt_proj_w[d]; dpb[d] = dt_proj_b[d];
        Dsk[d] = D_skip[d]; ow0[d] = out_proj_w[d]; ow1[d] = out_proj_w[4+d];
    }
    float xpw[17][4];
#pragma unroll
    for (int e = 0; e < 17; ++e)
#pragma unroll
        for (int d = 0; d < 4; ++d) xpw[e][d] = x_proj_w[4*e + d];

    const float LOG2E = 1.4426950408889634f;
    float A2[32];  // A * log2(e), A = -exp(A_log); a = exp2(dt * A2)
#pragma unroll
    for (int i = 0; i < 32; ++i) A2[i] = -__expf(A_log[i]) * LOG2E;

    // scan-role constants: lane lh -> (d,s) = (lh>>3, lh&7)
    const int   d_idx = lh >> 3;
    const float owd0  = out_proj_w[d_idx];
    const float owd1  = out_proj_w[4 + d_idx];

    float h = 0.0f;                                 // scan state h[d,s]
    float acc0 = 0.f, acc1 = 0.f;                   // scan-side feat partials
    float sacc0 = 0.f, sacc1 = 0.f;                 // skip-term partials

    // prefetch chunk 0 raw samples (t and t-1, both channels)
    float c0  = rp[lh];
    float c1  = rp[TT + lh];
    float c0m = (lh > 0) ? rp[lh - 1]      : 0.0f;  // t==0 -> causal pad
    float c1m = (lh > 0) ? rp[TT + lh - 1] : 0.0f;

    for (int chunk = 0; chunk < NCHUNK; ++chunk) {
        // software prefetch next chunk's raw
        float p0 = 0.f, p1 = 0.f, p0m = 0.f, p1m = 0.f;
        if (chunk + 1 < NCHUNK) {
            int tn = (chunk + 1) * TC + lh;   // tn >= 32, tn-1 always valid
            p0  = rp[tn];       p1  = rp[TT + tn];
            p0m = rp[tn - 1];   p1m = rp[TT + tn - 1];
        }

        // ---- pointwise phase: this lane handles timestep t = chunk*TC + lh ----
        float xz[8], xm1[4];
#pragma unroll
        for (int j = 0; j < 8; ++j) xz[j] = ipw[j][0]*c0 + ipw[j][1]*c1;
#pragma unroll
        for (int d = 0; d < 4; ++d) xm1[d] = ipw[d][0]*c0m + ipw[d][1]*c1m;

        float x[4], sz[4];
#pragma unroll
        for (int d = 0; d < 4; ++d) {
            float v = xm1[d]*cw0[d] + xz[d]*cw1[d] + cbv[d];  // causal conv k=2
            x[d] = v * fast_sigmoid(v);                        // silu
            float zv = xz[4 + d];
            sz[d] = zv * fast_sigmoid(zv);                     // silu(z)
        }

        float dtin = xpw[0][0]*x[0] + xpw[0][1]*x[1] + xpw[0][2]*x[2] + xpw[0][3]*x[3];
        float Bm[8], Cm[8];
#pragma unroll
        for (int s = 0; s < 8; ++s) {
            Bm[s] = xpw[1+s][0]*x[0] + xpw[1+s][1]*x[1] + xpw[1+s][2]*x[2] + xpw[1+s][3]*x[3];
            Cm[s] = xpw[9+s][0]*x[0] + xpw[9+s][1]*x[1] + xpw[9+s][2]*x[2] + xpw[9+s][3]*x[3];
        }

        float dtv[4];
#pragma unroll
        for (int d = 0; d < 4; ++d) {
            float v = dtin*dpw[d] + dpb[d];
            // stable softplus: max(v,0) + log(1 + exp(-|v|))
            dtv[d] = fmaxf(v, 0.0f) + __logf(1.0f + __expf(-fabsf(v)));
        }

#pragma unroll
        for (int d = 0; d < 4; ++d) {
            float dtx = dtv[d] * x[d];
#pragma unroll
            for (int s = 0; s < 8; ++s) {
                int ds = d*8 + s;
                float a = exp2f(dtv[d] * A2[ds]);      // deltaA
                float b = dtx * Bm[s];                 // deltaBx
                s_ab[abBase + lh*33 + ds] = make_float2(a, b);
                s_q [qBase  + lh*33 + ds] = Cm[s] * sz[d];
            }
            float g = x[d] * Dsk[d] * sz[d];           // skip term, folded here
            sacc0 = fmaf(g, ow0[d], sacc0);
            sacc1 = fmaf(g, ow1[d], sacc1);
        }

        __syncthreads();

        // ---- scan phase: this lane owns state element (d_idx, s_idx) ----
#pragma unroll
        for (int t2 = 0; t2 < TC; ++t2) {
            float2 ab = s_ab[abBase + t2*33 + lh];
            float  qq = s_q [qBase  + t2*33 + lh];
            h = fmaf(ab.x, h, ab.y);                   // h = a*h + b
            float hq = h * qq;                         // h * C[s] * silu(z)[d]
            acc0 = fmaf(hq, owd0, acc0);
            acc1 = fmaf(hq, owd1, acc1);
        }

        __syncthreads();  // LDS WAR before next pointwise overwrite

        c0 = p0; c1 = p1; c0m = p0m; c1m = p1m;
    }

    // feat[c] = (scan partials + skip partials) summed over the 32-lane half
    float tot0 = acc0 + sacc0;
    float tot1 = acc1 + sacc1;
#pragma unroll
    for (int m = 16; m >= 1; m >>= 1) {   // xor masks <32 stay within the half
        tot0 += __shfl_xor(tot0, m, 64);
        tot1 += __shfl_xor(tot1, m, 64);
    }
    float f0 = tot0 * (1.0f / (float)TT);
    float f1 = tot1 * (1.0f / (float)TT);

    // per-sequence head: relu(feat @ proj_w^T + b), then mean over 36 pairs
    if (lh < 16) {
        float pv = f0*proj_w[2*lh] + f1*proj_w[2*lh + 1] + proj_b[lh];
        pv = fmaxf(pv, 0.0f);
        atomicAdd(out + (n / NUM_PAIRS) * 16 + lh, pv * (1.0f / NUM_PAIRS));
    }
}

extern "C" void kernel_launch(void* const* d_in, const int* in_sizes, int n_in,
                              void* d_out, int out_size, void* d_ws, size_t ws_size,
                              hipStream_t stream)
{
    const float* raw        = (const float*)d_in[0];
    const float* in_proj_w  = (const float*)d_in[1];
    const float* conv_w     = (const float*)d_in[2];
    const float* conv_b     = (const float*)d_in[3];
    const float* x_proj_w   = (const float*)d_in[4];
    const float* dt_proj_w  = (const float*)d_in[5];
    const float* dt_proj_b  = (const float*)d_in[6];
    const float* A_log      = (const float*)d_in[7];
    const float* D_skip     = (const float*)d_in[8];
    const float* out_proj_w = (const float*)d_in[9];
    const float* proj_w     = (const float*)d_in[10];
    const float* proj_b     = (const float*)d_in[11];

    // d_out is re-poisoned before every timed replay; zero it (atomicAdd sink)
    hipMemsetAsync(d_out, 0, (size_t)out_size * sizeof(float), stream);

    pm_kernel<<<dim3(NSEQ / 2), dim3(64), 0, stream>>>(
        raw, in_proj_w, conv_w, conv_b, x_proj_w, dt_proj_w, dt_proj_b,
        A_log, D_skip, out_proj_w, proj_w, proj_b, (float*)d_out);
}

// Round 2
// 144.989 us; speedup vs baseline: 1.2962x; 1.2962x over previous
//
#include <hip/hip_runtime.h>

// PairwiseMamba: 2304 independent mamba scans (T=1024, d_inner=4, d_state=8).
// R1: time-parallel segmented scan. Block = 256 thr = 4 waves; wave g owns
// segment [g*256,(g+1)*256) of the block's 2 sequences (one per 32-lane half).
// Per 32-step chunk a wave alternates: pointwise (lane<->t) stages compact
// factors (dt,dtx,sz,B,C) to wave-private LDS; scan (lane<->(d,s)) accumulates
// the segment-local affine reduction (A_seg,B_seg,W,S). The h=a*h+b recurrence
// is affine, so feat contribution = h_in*W + S; segments compose with a G=4
// sequential tail. No __syncthreads in the hot loop (wave-private LDS +
// s_waitcnt lgkmcnt(0)); two barriers total for the cross-segment combine.

#define TT 1024
#define TC 32
#define GSEG 4
#define SEGLEN (TT / GSEG)            // 256
#define NCHUNK (SEGLEN / TC)          // 8
#define NUM_PAIRS 36
#define NSEQ 2304
#define ST 36                          // floats per t-slot (16B-aligned stride)
#define PER_HALF (TC * ST)             // 1152
#define HALF_SHIFT 16                  // destagger halves across banks
#define PER_WAVE (2 * PER_HALF + HALF_SHIFT)   // 2320
#define STAGE_TOTAL (GSEG * PER_WAVE)          // 9280
#define COMB_OFF STAGE_TOTAL
#define COMB_SZ (2 * GSEG * 32 * 2)            // (A,B) float2 per (half,g,ds)
#define PART_OFF (COMB_OFF + COMB_SZ)
#define PART_SZ (2 * GSEG * 2)                 // per-(half,g) partial (tot0,tot1)
#define LDS_TOTAL (PART_OFF + PART_SZ)         // 9808 floats = 39232 B -> 4 blk/CU

__device__ __forceinline__ float fast_sigmoid(float v) {
    return __builtin_amdgcn_rcpf(1.0f + __expf(-v));
}

__global__ __launch_bounds__(256, 4)
void pm_kernel(const float* __restrict__ raw,        // (N,2,T)
               const float* __restrict__ in_proj_w,  // (8,2)
               const float* __restrict__ conv_w,     // (4,2)
               const float* __restrict__ conv_b,     // (4)
               const float* __restrict__ x_proj_w,   // (17,4)
               const float* __restrict__ dt_proj_w,  // (4,1)
               const float* __restrict__ dt_proj_b,  // (4)
               const float* __restrict__ A_log,      // (4,8)
               const float* __restrict__ D_skip,     // (4)
               const float* __restrict__ out_proj_w, // (2,4)
               const float* __restrict__ proj_w,     // (16,2)
               const float* __restrict__ proj_b,     // (16)
               float* __restrict__ out)              // (64,16), pre-zeroed
{
    __shared__ float lds[LDS_TOTAL];

    const int tid  = threadIdx.x;
    const int wid  = tid >> 6;        // segment index g
    const int lane = tid & 63;
    const int half = lane >> 5;       // which of the block's 2 sequences
    const int lh   = lane & 31;       // pointwise: t-in-chunk; scan: ds = d*8+s
    const int n    = blockIdx.x * 2 + half;
    const float* rp = raw + (size_t)n * (2 * TT);

    float* stg = lds + wid * PER_WAVE + half * (PER_HALF + HALF_SHIFT);

    // ---- weights (wave-uniform loads) ----
    float ipw[8][2];
#pragma unroll
    for (int j = 0; j < 8; ++j) { ipw[j][0] = in_proj_w[2*j]; ipw[j][1] = in_proj_w[2*j+1]; }
    float cw0[4], cw1[4], cbv[4], dpw[4], dpb[4], Dsk[4], ow0[4], ow1[4];
#pragma unroll
    for (int d = 0; d < 4; ++d) {
        cw0[d] = conv_w[2*d]; cw1[d] = conv_w[2*d+1]; cbv[d] = conv_b[d];
        dpw[d] = dt_proj_w[d]; dpb[d] = dt_proj_b[d];
        Dsk[d] = D_skip[d]; ow0[d] = out_proj_w[d]; ow1[d] = out_proj_w[4+d];
    }
    float xpw[17][4];
#pragma unroll
    for (int e = 0; e < 17; ++e)
#pragma unroll
        for (int d = 0; d < 4; ++d) xpw[e][d] = x_proj_w[4*e + d];

    const float LOG2E = 1.4426950408889634f;
    // scan-role constants: lane lh -> (d,s)
    const int   d_idx = lh >> 3;
    const int   s_idx = lh & 7;
    const float A2ds  = -__expf(A_log[lh]) * LOG2E;   // a = exp2(dt * A2ds)
    const float owd0  = out_proj_w[d_idx];
    const float owd1  = out_proj_w[4 + d_idx];

    // segment-local affine reduction state (per ds lane)
    float A_run = 1.0f, hB = 0.0f, W = 0.0f, S = 0.0f;
    float sacc0 = 0.f, sacc1 = 0.f;                    // skip-term partials

    const int seg0 = wid * SEGLEN;

    // prefetch chunk 0 raw samples (t and t-1, both channels)
    int t0 = seg0 + lh;
    float c0  = rp[t0];
    float c1  = rp[TT + t0];
    float c0m = (t0 > 0) ? rp[t0 - 1]      : 0.0f;     // causal pad at t==0
    float c1m = (t0 > 0) ? rp[TT + t0 - 1] : 0.0f;

    for (int chunk = 0; chunk < NCHUNK; ++chunk) {
        // software prefetch next chunk's raw
        float p0 = 0.f, p1 = 0.f, p0m = 0.f, p1m = 0.f;
        if (chunk + 1 < NCHUNK) {
            int tn = seg0 + (chunk + 1) * TC + lh;     // tn >= 32 -> tn-1 valid
            p0  = rp[tn];       p1  = rp[TT + tn];
            p0m = rp[tn - 1];   p1m = rp[TT + tn - 1];
        }

        // ---- pointwise phase: this lane handles t = seg0 + chunk*TC + lh ----
        float xz[8], xm1[4];
#pragma unroll
        for (int j = 0; j < 8; ++j) xz[j] = ipw[j][0]*c0 + ipw[j][1]*c1;
#pragma unroll
        for (int d = 0; d < 4; ++d) xm1[d] = ipw[d][0]*c0m + ipw[d][1]*c1m;

        float x[4], sz[4];
#pragma unroll
        for (int d = 0; d < 4; ++d) {
            float v = xm1[d]*cw0[d] + xz[d]*cw1[d] + cbv[d];   // causal conv k=2
            x[d] = v * fast_sigmoid(v);                         // silu
            float zv = xz[4 + d];
            sz[d] = zv * fast_sigmoid(zv);                      // silu(z)
        }

        float dtin = xpw[0][0]*x[0] + xpw[0][1]*x[1] + xpw[0][2]*x[2] + xpw[0][3]*x[3];
        float Bm[8], Cm[8];
#pragma unroll
        for (int s = 0; s < 8; ++s) {
            Bm[s] = xpw[1+s][0]*x[0] + xpw[1+s][1]*x[1] + xpw[1+s][2]*x[2] + xpw[1+s][3]*x[3];
            Cm[s] = xpw[9+s][0]*x[0] + xpw[9+s][1]*x[1] + xpw[9+s][2]*x[2] + xpw[9+s][3]*x[3];
        }

        float* slot = stg + lh * ST;
#pragma unroll
        for (int d = 0; d < 4; ++d) {
            float v = dtin*dpw[d] + dpb[d];
            // stable softplus: max(v,0) + log(1 + exp(-|v|))
            float dt = fmaxf(v, 0.0f) + __logf(1.0f + __expf(-fabsf(v)));
            *(float4*)(slot + 4*d) = make_float4(dt, dt * x[d], sz[d], 0.0f);
            float g = x[d] * Dsk[d] * sz[d];                    // skip term
            sacc0 = fmaf(g, ow0[d], sacc0);
            sacc1 = fmaf(g, ow1[d], sacc1);
        }
#pragma unroll
        for (int s = 0; s < 8; ++s)
            *(float2*)(slot + 16 + 2*s) = make_float2(Bm[s], Cm[s]);

        // wave-private LDS: drain writes before same-wave reads (no barrier)
        __asm__ volatile("s_waitcnt lgkmcnt(0)" ::: "memory");

        // ---- scan phase: lane owns (d_idx, s_idx); local affine reduction ----
#pragma unroll
        for (int t2 = 0; t2 < TC; ++t2) {
            const float* sl = stg + t2 * ST;
            float4 dv = *(const float4*)(sl + 4*d_idx);         // dt, dtx, sz
            float2 bc = *(const float2*)(sl + 16 + 2*s_idx);    // B, C
            float a = exp2f(dv.x * A2ds);
            float b = dv.y * bc.x;
            float q = bc.y * dv.z;
            A_run *= a;                  // running product  П a
            hB = fmaf(a, hB, b);         // local scan, h_in = 0
            W  = fmaf(A_run, q, W);      // h_in-coupling coefficient
            S  = fmaf(hB, q, S);         // h_in-independent contribution
        }

        // reads done before next chunk's writes overwrite the slots
        __asm__ volatile("s_waitcnt lgkmcnt(0)" ::: "memory");

        c0 = p0; c1 = p1; c0m = p0m; c1m = p1m;
    }

    // ---- cross-segment combine ----
    float* comb = lds + COMB_OFF;
    *(float2*)(comb + ((half*GSEG + wid)*32 + lh)*2) = make_float2(A_run, hB);
    __syncthreads();

    // each wave composes the segments before it to get its h_in (wid uniform)
    float h_in = 0.0f;
#pragma unroll
    for (int g = 0; g < GSEG; ++g) {
        if (g < wid) {
            float2 abg = *(const float2*)(comb + ((half*GSEG + g)*32 + lh)*2);
            h_in = fmaf(abg.x, h_in, abg.y);
        }
    }

    float F = fmaf(h_in, W, S);          // this segment's Σ_t h_t q_t for (d,s)
    float tot0 = fmaf(F, owd0, sacc0);
    float tot1 = fmaf(F, owd1, sacc1);
#pragma unroll
    for (int m = 16; m >= 1; m >>= 1) {  // reduce within the 32-lane half
        tot0 += __shfl_xor(tot0, m, 64);
        tot1 += __shfl_xor(tot1, m, 64);
    }
    float* part = lds + PART_OFF;
    if (lh == 0) {
        part[(half*GSEG + wid)*2]     = tot0;
        part[(half*GSEG + wid)*2 + 1] = tot1;
    }
    __syncthreads();

    // wave 0: sum segment partials, head projection, mean over pairs
    if (wid == 0 && lh < 16) {
        float f0 = 0.f, f1 = 0.f;
#pragma unroll
        for (int g = 0; g < GSEG; ++g) {
            f0 += part[(half*GSEG + g)*2];
            f1 += part[(half*GSEG + g)*2 + 1];
        }
        f0 *= (1.0f / (float)TT);
        f1 *= (1.0f / (float)TT);
        float pv = f0*proj_w[2*lh] + f1*proj_w[2*lh + 1] + proj_b[lh];
        pv = fmaxf(pv, 0.0f);
        atomicAdd(out + (n / NUM_PAIRS) * 16 + lh, pv * (1.0f / NUM_PAIRS));
    }
}

extern "C" void kernel_launch(void* const* d_in, const int* in_sizes, int n_in,
                              void* d_out, int out_size, void* d_ws, size_t ws_size,
                              hipStream_t stream)
{
    const float* raw        = (const float*)d_in[0];
    const float* in_proj_w  = (const float*)d_in[1];
    const float* conv_w     = (const float*)d_in[2];
    const float* conv_b     = (const float*)d_in[3];
    const float* x_proj_w   = (const float*)d_in[4];
    const float* dt_proj_w  = (const float*)d_in[5];
    const float* dt_proj_b  = (const float*)d_in[6];
    const float* A_log      = (const float*)d_in[7];
    const float* D_skip     = (const float*)d_in[8];
    const float* out_proj_w = (const float*)d_in[9];
    const float* proj_w     = (const float*)d_in[10];
    const float* proj_b     = (const float*)d_in[11];

    // d_out is re-poisoned before every timed replay; zero it (atomicAdd sink)
    hipMemsetAsync(d_out, 0, (size_t)out_size * sizeof(float), stream);

    pm_kernel<<<dim3(NSEQ / 2), dim3(256), 0, stream>>>(
        raw, in_proj_w, conv_w, conv_b, x_proj_w, dt_proj_w, dt_proj_b,
        A_log, D_skip, out_proj_w, proj_w, proj_b, (float*)d_out);
}

// Round 3
// 133.384 us; speedup vs baseline: 1.4090x; 1.0870x over previous
//
#include <hip/hip_runtime.h>
#include <hip/hip_fp16.h>

// PairwiseMamba: 2304 independent mamba scans (T=1024, d_inner=4, d_state=8).
// R2: GSEG=8 time-parallel segmented scan (512-thr blocks, 8 waves), packed
// fp32 math (v_pk_fma_f32) in scan + pointwise, 96B staging slots (dt/dtx/sz
// fp32 + B,C as half2) -> 3 blocks/CU = 24 waves/CU. Wave-private staging, no
// barriers in the hot loop; combine buffers alias dead staging after barrier.

typedef float v2f __attribute__((ext_vector_type(2)));

#define TT 1024
#define TC 32
#define GSEG 8
#define SEGLEN (TT / GSEG)             // 128
#define NCHUNK (SEGLEN / TC)           // 4
#define NUM_PAIRS 36
#define NSEQ 2304

#define SLOTF 24                        // floats per t-slot (96 B)
#define PER_HALF (TC * SLOTF)           // 768 floats (mult of 32 -> bank-stable)
#define HALF_SHIFT 16                   // bank-destagger the two halves
#define PER_WAVE (2 * PER_HALF + HALF_SHIFT)   // 1552 floats
#define STAGE_TOTAL (GSEG * PER_WAVE)          // 12416 floats = 49664 B

__device__ __forceinline__ float fast_silu(float v) {
    float e = __builtin_amdgcn_exp2f(v * -1.4426950408889634f);
    return v * __builtin_amdgcn_rcpf(1.0f + e);
}

__global__ __launch_bounds__(512, 6)
void pm_kernel(const float* __restrict__ raw,        // (N,2,T)
               const float* __restrict__ in_proj_w,  // (8,2)
               const float* __restrict__ conv_w,     // (4,2)
               const float* __restrict__ conv_b,     // (4)
               const float* __restrict__ x_proj_w,   // (17,4)
               const float* __restrict__ dt_proj_w,  // (4,1)
               const float* __restrict__ dt_proj_b,  // (4)
               const float* __restrict__ A_log,      // (4,8)
               const float* __restrict__ D_skip,     // (4)
               const float* __restrict__ out_proj_w, // (2,4)
               const float* __restrict__ proj_w,     // (16,2)
               const float* __restrict__ proj_b,     // (16)
               float* __restrict__ out)              // (64,16), pre-zeroed
{
    __shared__ float lds[STAGE_TOTAL];

    const int tid  = threadIdx.x;
    const int wid  = tid >> 6;        // segment index g (0..7)
    const int lane = tid & 63;
    const int half = lane >> 5;       // which of the block's 2 sequences
    const int lh   = lane & 31;       // pointwise: t-in-chunk; scan: ds = d*8+s
    const int n    = blockIdx.x * 2 + half;
    const float* rp = raw + (size_t)n * (2 * TT);

    float* stg = lds + wid * PER_WAVE + half * (PER_HALF + HALF_SHIFT);

    // ---- weights (uniform indexing -> scalarized to SGPRs) ----
    v2f ipc0[4], ipc1[4];    // pair (j=2k, 2k+1) of in_proj rows
#pragma unroll
    for (int k = 0; k < 4; ++k) {
        ipc0[k] = (v2f){in_proj_w[4*k],     in_proj_w[4*k + 2]};
        ipc1[k] = (v2f){in_proj_w[4*k + 1], in_proj_w[4*k + 3]};
    }
    v2f cw0p[2], cw1p[2], cbp[2];
#pragma unroll
    for (int k = 0; k < 2; ++k) {
        cw0p[k] = (v2f){conv_w[4*k],     conv_w[4*k + 2]};
        cw1p[k] = (v2f){conv_w[4*k + 1], conv_w[4*k + 3]};
        cbp[k]  = (v2f){conv_b[2*k],     conv_b[2*k + 1]};
    }
    float dpw[4], dpb[4], xp0[4];
    v2f owp[4];   // {out_proj_w[0][d], out_proj_w[1][d]}
    float Dsk[4];
#pragma unroll
    for (int d = 0; d < 4; ++d) {
        dpw[d] = dt_proj_w[d]; dpb[d] = dt_proj_b[d];
        xp0[d] = x_proj_w[d];  Dsk[d] = D_skip[d];
        owp[d] = (v2f){out_proj_w[d], out_proj_w[4 + d]};
    }
    v2f xbc[8][4];  // {x_proj_w[1+s][d], x_proj_w[9+s][d]}
#pragma unroll
    for (int s = 0; s < 8; ++s)
#pragma unroll
        for (int d = 0; d < 4; ++d)
            xbc[s][d] = (v2f){x_proj_w[4*(1+s) + d], x_proj_w[4*(9+s) + d]};

    const float LOG2E = 1.4426950408889634f;
    // scan-role constants: lane lh -> (d,s)
    const int   d_idx = lh >> 3;
    const int   s_idx = lh & 7;
    const float A2ds  = -__expf(A_log[lh]) * LOG2E;   // a = exp2(dt * A2ds)
    const v2f   owd   = (v2f){out_proj_w[d_idx], out_proj_w[4 + d_idx]};

    // segment-local affine reduction state (per ds lane), packed
    v2f AhB = {1.0f, 0.0f};   // (A_run, hB)
    v2f WS  = {0.0f, 0.0f};   // (W, S)
    v2f sacc = {0.0f, 0.0f};  // skip-term partials (ow row 0, row 1)

    const int seg0 = wid * SEGLEN;

    // prefetch chunk 0 raw samples (t and t-1, both channels)
    int t0 = seg0 + lh;
    float c0  = rp[t0];
    float c1  = rp[TT + t0];
    float c0m = (t0 > 0) ? rp[t0 - 1]      : 0.0f;     // causal pad at t==0
    float c1m = (t0 > 0) ? rp[TT + t0 - 1] : 0.0f;

    for (int chunk = 0; chunk < NCHUNK; ++chunk) {
        // software prefetch next chunk's raw
        float p0 = 0.f, p1 = 0.f, p0m = 0.f, p1m = 0.f;
        if (chunk + 1 < NCHUNK) {
            int tn = seg0 + (chunk + 1) * TC + lh;     // tn >= 32 -> tn-1 valid
            p0  = rp[tn];       p1  = rp[TT + tn];
            p0m = rp[tn - 1];   p1m = rp[TT + tn - 1];
        }

        // ---- pointwise phase: this lane handles t = seg0 + chunk*TC + lh ----
        const v2f c0v = {c0, c0}, c1v = {c1, c1}, c0mv = {c0m, c0m}, c1mv = {c1m, c1m};
        v2f xzp[4], xm1p[2];
#pragma unroll
        for (int k = 0; k < 4; ++k)
            xzp[k] = __builtin_elementwise_fma(ipc0[k], c0v, ipc1[k] * c1v);
#pragma unroll
        for (int k = 0; k < 2; ++k)
            xm1p[k] = __builtin_elementwise_fma(ipc0[k], c0mv, ipc1[k] * c1mv);

        float x[4], sz[4];
#pragma unroll
        for (int k = 0; k < 2; ++k) {
            v2f v = __builtin_elementwise_fma(xm1p[k], cw0p[k],
                    __builtin_elementwise_fma(xzp[k], cw1p[k], cbp[k]));
            x[2*k]   = fast_silu(v.x);
            x[2*k+1] = fast_silu(v.y);
            sz[2*k]   = fast_silu(xzp[2 + k].x);
            sz[2*k+1] = fast_silu(xzp[2 + k].y);
        }

        float dtin = xp0[0]*x[0] + xp0[1]*x[1] + xp0[2]*x[2] + xp0[3]*x[3];
        v2f bc[8];
#pragma unroll
        for (int s = 0; s < 8; ++s) {
            v2f a = xbc[s][0] * (v2f){x[0], x[0]};
            a = __builtin_elementwise_fma(xbc[s][1], (v2f){x[1], x[1]}, a);
            a = __builtin_elementwise_fma(xbc[s][2], (v2f){x[2], x[2]}, a);
            bc[s] = __builtin_elementwise_fma(xbc[s][3], (v2f){x[3], x[3]}, a);
        }

        float* slot = stg + lh * SLOTF;
#pragma unroll
        for (int d = 0; d < 4; ++d) {
            float u = dtin*dpw[d] + dpb[d];
            // stable softplus: max(u,0) + log(1 + exp(-|u|))
            float dt = fmaxf(u, 0.0f) + __logf(1.0f + __expf(-fabsf(u)));
            *(float4*)(slot + 4*d) = make_float4(dt, dt * x[d], sz[d], 0.0f);
            float g = x[d] * Dsk[d] * sz[d];                    // skip term
            sacc = __builtin_elementwise_fma((v2f){g, g}, owp[d], sacc);
        }
        uint4 ubc0, ubc1;
        {
            __half2 h0 = __floats2half2_rn(bc[0].x, bc[0].y);
            __half2 h1 = __floats2half2_rn(bc[1].x, bc[1].y);
            __half2 h2 = __floats2half2_rn(bc[2].x, bc[2].y);
            __half2 h3 = __floats2half2_rn(bc[3].x, bc[3].y);
            __half2 h4 = __floats2half2_rn(bc[4].x, bc[4].y);
            __half2 h5 = __floats2half2_rn(bc[5].x, bc[5].y);
            __half2 h6 = __floats2half2_rn(bc[6].x, bc[6].y);
            __half2 h7 = __floats2half2_rn(bc[7].x, bc[7].y);
            ubc0 = make_uint4(*(uint*)&h0, *(uint*)&h1, *(uint*)&h2, *(uint*)&h3);
            ubc1 = make_uint4(*(uint*)&h4, *(uint*)&h5, *(uint*)&h6, *(uint*)&h7);
        }
        *(uint4*)(slot + 16) = ubc0;
        *(uint4*)(slot + 20) = ubc1;

        // wave-private LDS: drain writes before same-wave reads (no barrier)
        __asm__ volatile("s_waitcnt lgkmcnt(0)" ::: "memory");

        // ---- scan phase: lane owns (d_idx, s_idx); local affine reduction ----
#pragma unroll
        for (int t2 = 0; t2 < TC; ++t2) {
            const float* sl = stg + t2 * SLOTF;
            float4 f = *(const float4*)(sl + 4*d_idx);          // dt, dtx, sz
            uint ub  = *(const uint*)(sl + 16 + s_idx);         // half2(B, C)
            float2 bcf = __half22float2(*(__half2*)&ub);
            float a = __builtin_amdgcn_exp2f(f.x * A2ds);
            float b = f.y * bcf.x;
            float q = f.z * bcf.y;
            AhB = __builtin_elementwise_fma((v2f){a, a}, AhB, (v2f){0.0f, b});
            WS  = __builtin_elementwise_fma(AhB, (v2f){q, q}, WS);
        }

        // reads done before next chunk's writes overwrite the slots
        __asm__ volatile("s_waitcnt lgkmcnt(0)" ::: "memory");

        c0 = p0; c1 = p1; c0m = p0m; c1m = p1m;
    }

    // ---- cross-segment combine (aliases dead staging LDS, post-barrier) ----
    __syncthreads();
    float2* comb = (float2*)lds;                       // 2*8*32 float2 = 2048 floats
    comb[(half*GSEG + wid)*32 + lh] = make_float2(AhB.x, AhB.y);
    __syncthreads();

    // each wave composes the segments before it to get its h_in (wid uniform)
    float h_in = 0.0f;
#pragma unroll
    for (int g = 0; g < GSEG; ++g) {
        if (g < wid) {
            float2 abg = comb[(half*GSEG + g)*32 + lh];
            h_in = fmaf(abg.x, h_in, abg.y);
        }
    }

    float F = fmaf(h_in, WS.x, WS.y);    // this segment's Σ_t h_t q_t for (d,s)
    v2f tot = __builtin_elementwise_fma((v2f){F, F}, owd, sacc);
    float tot0 = tot.x, tot1 = tot.y;
#pragma unroll
    for (int m = 16; m >= 1; m >>= 1) {  // reduce within the 32-lane half
        tot0 += __shfl_xor(tot0, m, 64);
        tot1 += __shfl_xor(tot1, m, 64);
    }
    float* part = lds + 2048;            // after comb region
    if (lh == 0) {
        part[(half*GSEG + wid)*2]     = tot0;
        part[(half*GSEG + wid)*2 + 1] = tot1;
    }
    __syncthreads();

    // wave 0: sum segment partials, head projection, mean over pairs
    if (wid == 0 && lh < 16) {
        float f0 = 0.f, f1 = 0.f;
#pragma unroll
        for (int g = 0; g < GSEG; ++g) {
            f0 += part[(half*GSEG + g)*2];
            f1 += part[(half*GSEG + g)*2 + 1];
        }
        f0 *= (1.0f / (float)TT);
        f1 *= (1.0f / (float)TT);
        float pv = f0*proj_w[2*lh] + f1*proj_w[2*lh + 1] + proj_b[lh];
        pv = fmaxf(pv, 0.0f);
        atomicAdd(out + (n / NUM_PAIRS) * 16 + lh, pv * (1.0f / NUM_PAIRS));
    }
}

extern "C" void kernel_launch(void* const* d_in, const int* in_sizes, int n_in,
                              void* d_out, int out_size, void* d_ws, size_t ws_size,
                              hipStream_t stream)
{
    const float* raw        = (const float*)d_in[0];
    const float* in_proj_w  = (const float*)d_in[1];
    const float* conv_w     = (const float*)d_in[2];
    const float* conv_b     = (const float*)d_in[3];
    const float* x_proj_w   = (const float*)d_in[4];
    const float* dt_proj_w  = (const float*)d_in[5];
    const float* dt_proj_b  = (const float*)d_in[6];
    const float* A_log      = (const float*)d_in[7];
    const float* D_skip     = (const float*)d_in[8];
    const float* out_proj_w = (const float*)d_in[9];
    const float* proj_w     = (const float*)d_in[10];
    const float* proj_b     = (const float*)d_in[11];

    // d_out is re-poisoned before every timed replay; zero it (atomicAdd sink)
    hipMemsetAsync(d_out, 0, (size_t)out_size * sizeof(float), stream);

    pm_kernel<<<dim3(NSEQ / 2), dim3(512), 0, stream>>>(
        raw, in_proj_w, conv_w, conv_b, x_proj_w, dt_proj_w, dt_proj_b,
        A_log, D_skip, out_proj_w, proj_w, proj_b, (float*)d_out);
}

// Round 4
// 126.746 us; speedup vs baseline: 1.4828x; 1.0524x over previous
//
#include <hip/hip_runtime.h>
#include <hip/hip_fp16.h>

// PairwiseMamba: 2304 independent mamba scans (T=1024, d_inner=4, d_state=8).
// R3: GSEG=8 segmented affine scan (512-thr blocks). SoA LDS staging, 64B/t:
//   DT[t][d] fp32   - write lane-consecutive float4 (conflict-free), read bcast
//   DS[t][d] half2(dtx,sz) - write lane-consecutive uint4, read b32 bcast
//   BC[s][t] half2(B,C), row stride 33 - write 8 lane-consecutive b32,
//                                        read banks (s+t)%32 (free)
// Halves destaggered 16 banks. 33.8KB/block -> 4 blocks/CU = 32 waves/CU.
// No fences in hot loop (same-wave LDS ordering is a compiler-visible dep).
// cvt_pkrtz packs, fast softplus, scalar 4-fma scan update.

typedef float v2f __attribute__((ext_vector_type(2)));

#define TT 1024
#define TC 32
#define GSEG 8
#define SEGLEN (TT / GSEG)             // 128
#define NCHUNK (SEGLEN / TC)           // 4
#define NUM_PAIRS 36
#define NSEQ 2304

// per-half staging layout (float/uint slots): DT [0,128), DS [128,256), BC [256,520)
#define DT_OFF 0
#define DS_OFF 128
#define BC_OFF 256
#define BC_STRIDE 33                   // half2 slots per BC row (pad -> bank spread)
#define PER_HALF_STRIDE 528            // floats; %32==16 -> halves bank-disjoint
#define PER_WAVE (2 * PER_HALF_STRIDE) // 1056 floats
#define STAGE_TOTAL (GSEG * PER_WAVE)  // 8448 floats = 33792 B

__device__ __forceinline__ float fast_silu(float v) {
    float e = __builtin_amdgcn_exp2f(v * -1.4426950408889634f);
    return v * __builtin_amdgcn_rcpf(1.0f + e);
}
// softplus, direct form: log(1+exp(v)). Safe: |v| << 80 here (inputs O(1),
// weights ~0.5 scale -> |v| <~ 20); exp2 underflow/overflow impossible.
__device__ __forceinline__ float fast_softplus(float v) {
    float e = __builtin_amdgcn_exp2f(v * 1.4426950408889634f);
    return __builtin_amdgcn_logf(1.0f + e) * 0.6931471805599453f;
}
__device__ __forceinline__ uint pk_h2(float a, float b) {
    return __builtin_bit_cast(uint, __builtin_amdgcn_cvt_pkrtz(a, b));
}

__global__ __launch_bounds__(512, 6)
void pm_kernel(const float* __restrict__ raw,        // (N,2,T)
               const float* __restrict__ in_proj_w,  // (8,2)
               const float* __restrict__ conv_w,     // (4,2)
               const float* __restrict__ conv_b,     // (4)
               const float* __restrict__ x_proj_w,   // (17,4)
               const float* __restrict__ dt_proj_w,  // (4,1)
               const float* __restrict__ dt_proj_b,  // (4)
               const float* __restrict__ A_log,      // (4,8)
               const float* __restrict__ D_skip,     // (4)
               const float* __restrict__ out_proj_w, // (2,4)
               const float* __restrict__ proj_w,     // (16,2)
               const float* __restrict__ proj_b,     // (16)
               float* __restrict__ out)              // (64,16), pre-zeroed
{
    __shared__ float lds[STAGE_TOTAL];

    const int tid  = threadIdx.x;
    const int wid  = tid >> 6;        // segment index g (0..7)
    const int lane = tid & 63;
    const int half = lane >> 5;       // which of the block's 2 sequences
    const int lh   = lane & 31;       // pointwise: t-in-chunk; scan: ds = d*8+s
    const int n    = blockIdx.x * 2 + half;
    const float* rp = raw + (size_t)n * (2 * TT);

    float* hb = lds + wid * PER_WAVE + half * PER_HALF_STRIDE;

    // ---- weights (wave-uniform -> scalarized) ----
    float ip0[8], ip1[8];
#pragma unroll
    for (int j = 0; j < 8; ++j) { ip0[j] = in_proj_w[2*j]; ip1[j] = in_proj_w[2*j+1]; }
    float cw0[4], cw1[4], cbv[4], dpw[4], dpb[4], Dsk[4], ow0[4], ow1[4], xp0[4];
#pragma unroll
    for (int d = 0; d < 4; ++d) {
        cw0[d] = conv_w[2*d]; cw1[d] = conv_w[2*d+1]; cbv[d] = conv_b[d];
        dpw[d] = dt_proj_w[d]; dpb[d] = dt_proj_b[d];
        Dsk[d] = D_skip[d]; ow0[d] = out_proj_w[d]; ow1[d] = out_proj_w[4+d];
        xp0[d] = x_proj_w[d];
    }
    v2f xbc[8][4];  // {x_proj_w[1+s][d], x_proj_w[9+s][d]}
#pragma unroll
    for (int s = 0; s < 8; ++s)
#pragma unroll
        for (int d = 0; d < 4; ++d)
            xbc[s][d] = (v2f){x_proj_w[4*(1+s) + d], x_proj_w[4*(9+s) + d]};

    const float LOG2E = 1.4426950408889634f;
    // scan-role constants: lane lh -> (d,s)
    const int   d_idx = lh >> 3;
    const int   s_idx = lh & 7;
    const float A2ds  = -__expf(A_log[lh]) * LOG2E;   // a = exp2(dt * A2ds)
    const float owd0  = out_proj_w[d_idx];
    const float owd1  = out_proj_w[4 + d_idx];

    // hoisted scan read pointers (imm offsets inside the loop)
    const float* dtp = hb + DT_OFF + d_idx;              // [t2*4]
    const uint*  dsp = (const uint*)(hb + DS_OFF) + d_idx;   // [t2*4]
    const uint*  bcp = (const uint*)(hb + BC_OFF) + s_idx * BC_STRIDE; // [t2]

    // segment-local affine reduction state (per ds lane)
    float A_run = 1.0f, hB = 0.0f, W = 0.0f, S = 0.0f;
    float sacc0 = 0.f, sacc1 = 0.f;                    // skip-term partials

    const int seg0 = wid * SEGLEN;

    // prefetch chunk 0 raw samples (t and t-1, both channels)
    int t0 = seg0 + lh;
    float c0  = rp[t0];
    float c1  = rp[TT + t0];
    float c0m = (t0 > 0) ? rp[t0 - 1]      : 0.0f;     // causal pad at t==0
    float c1m = (t0 > 0) ? rp[TT + t0 - 1] : 0.0f;

    for (int chunk = 0; chunk < NCHUNK; ++chunk) {
        // software prefetch next chunk's raw
        float p0 = 0.f, p1 = 0.f, p0m = 0.f, p1m = 0.f;
        if (chunk + 1 < NCHUNK) {
            int tn = seg0 + (chunk + 1) * TC + lh;     // tn >= 32 -> tn-1 valid
            p0  = rp[tn];       p1  = rp[TT + tn];
            p0m = rp[tn - 1];   p1m = rp[TT + tn - 1];
        }

        // ---- pointwise: this lane handles t = seg0 + chunk*TC + lh ----
        float x[4], sz[4];
#pragma unroll
        for (int d = 0; d < 4; ++d) {
            float xz  = ip0[d]*c0  + ip1[d]*c1;
            float xm1 = ip0[d]*c0m + ip1[d]*c1m;
            float zv  = ip0[4+d]*c0 + ip1[4+d]*c1;
            float v   = xm1*cw0[d] + xz*cw1[d] + cbv[d];   // causal conv k=2
            x[d]  = fast_silu(v);
            sz[d] = fast_silu(zv);
        }

        float dtin = xp0[0]*x[0] + xp0[1]*x[1] + xp0[2]*x[2] + xp0[3]*x[3];

        v2f bc[8];
#pragma unroll
        for (int s = 0; s < 8; ++s) {
            v2f a = xbc[s][0] * (v2f){x[0], x[0]};
            a = __builtin_elementwise_fma(xbc[s][1], (v2f){x[1], x[1]}, a);
            a = __builtin_elementwise_fma(xbc[s][2], (v2f){x[2], x[2]}, a);
            bc[s] = __builtin_elementwise_fma(xbc[s][3], (v2f){x[3], x[3]}, a);
        }

        float dt[4];
#pragma unroll
        for (int d = 0; d < 4; ++d) {
            dt[d] = fast_softplus(dtin*dpw[d] + dpb[d]);
            float g = x[d] * Dsk[d] * sz[d];               // skip term
            sacc0 = fmaf(g, ow0[d], sacc0);
            sacc1 = fmaf(g, ow1[d], sacc1);
        }

        // stage: DT (float4, lane-consecutive), DS (uint4), BC (8x b32)
        *(float4*)(hb + DT_OFF + lh*4) = make_float4(dt[0], dt[1], dt[2], dt[3]);
        *(uint4*)((uint*)(hb + DS_OFF) + lh*4) =
            make_uint4(pk_h2(dt[0]*x[0], sz[0]), pk_h2(dt[1]*x[1], sz[1]),
                       pk_h2(dt[2]*x[2], sz[2]), pk_h2(dt[3]*x[3], sz[3]));
        uint* bcw = (uint*)(hb + BC_OFF) + lh;
#pragma unroll
        for (int s = 0; s < 8; ++s)
            bcw[s * BC_STRIDE] = pk_h2(bc[s].x, bc[s].y);

        // ---- scan: lane owns (d_idx, s_idx); local affine reduction ----
        // (same-wave LDS RAW: compiler orders via its own waitcnt insertion)
#pragma unroll
        for (int t2 = 0; t2 < TC; ++t2) {
            float dtv = dtp[t2*4];                          // broadcast b32
            uint  uds = dsp[t2*4];                          // half2(dtx, sz)
            uint  ubc = bcp[t2];                            // half2(B, C)
            __half2 prod = __hmul2(__builtin_bit_cast(__half2, uds),
                                   __builtin_bit_cast(__half2, ubc));
            float b = __half2float(__low2half(prod));       // dtx*B
            float q = __half2float(__high2half(prod));      // sz*C
            float a = __builtin_amdgcn_exp2f(dtv * A2ds);
            A_run *= a;                    // running product  П a
            hB = fmaf(a, hB, b);           // local scan, h_in = 0
            W  = fmaf(A_run, q, W);        // h_in-coupling coefficient
            S  = fmaf(hB, q, S);           // h_in-independent contribution
        }

        c0 = p0; c1 = p1; c0m = p0m; c1m = p1m;
    }

    // ---- cross-segment combine (aliases dead staging LDS, post-barrier) ----
    __syncthreads();
    float2* comb = (float2*)lds;                       // 2*8*32 float2
    comb[(half*GSEG + wid)*32 + lh] = make_float2(A_run, hB);
    __syncthreads();

    // each wave composes the segments before it to get its h_in (wid uniform)
    float h_in = 0.0f;
#pragma unroll
    for (int g = 0; g < GSEG; ++g) {
        if (g < wid) {
            float2 abg = comb[(half*GSEG + g)*32 + lh];
            h_in = fmaf(abg.x, h_in, abg.y);
        }
    }

    float F = fmaf(h_in, W, S);          // this segment's Σ_t h_t q_t for (d,s)
    float tot0 = fmaf(F, owd0, sacc0);
    float tot1 = fmaf(F, owd1, sacc1);
#pragma unroll
    for (int m = 16; m >= 1; m >>= 1) {  // reduce within the 32-lane half
        tot0 += __shfl_xor(tot0, m, 64);
        tot1 += __shfl_xor(tot1, m, 64);
    }
    float* part = lds + 2048;            // after comb region
    if (lh == 0) {
        part[(half*GSEG + wid)*2]     = tot0;
        part[(half*GSEG + wid)*2 + 1] = tot1;
    }
    __syncthreads();

    // wave 0: sum segment partials, head projection, mean over pairs
    if (wid == 0 && lh < 16) {
        float f0 = 0.f, f1 = 0.f;
#pragma unroll
        for (int g = 0; g < GSEG; ++g) {
            f0 += part[(half*GSEG + g)*2];
            f1 += part[(half*GSEG + g)*2 + 1];
        }
        f0 *= (1.0f / (float)TT);
        f1 *= (1.0f / (float)TT);
        float pv = f0*proj_w[2*lh] + f1*proj_w[2*lh + 1] + proj_b[lh];
        pv = fmaxf(pv, 0.0f);
        atomicAdd(out + (n / NUM_PAIRS) * 16 + lh, pv * (1.0f / NUM_PAIRS));
    }
}

extern "C" void kernel_launch(void* const* d_in, const int* in_sizes, int n_in,
                              void* d_out, int out_size, void* d_ws, size_t ws_size,
                              hipStream_t stream)
{
    const float* raw        = (const float*)d_in[0];
    const float* in_proj_w  = (const float*)d_in[1];
    const float* conv_w     = (const float*)d_in[2];
    const float* conv_b     = (const float*)d_in[3];
    const float* x_proj_w   = (const float*)d_in[4];
    const float* dt_proj_w  = (const float*)d_in[5];
    const float* dt_proj_b  = (const float*)d_in[6];
    const float* A_log      = (const float*)d_in[7];
    const float* D_skip     = (const float*)d_in[8];
    const float* out_proj_w = (const float*)d_in[9];
    const float* proj_w     = (const float*)d_in[10];
    const float* proj_b     = (const float*)d_in[11];

    // d_out is re-poisoned before every timed replay; zero it (atomicAdd sink)
    hipMemsetAsync(d_out, 0, (size_t)out_size * sizeof(float), stream);

    pm_kernel<<<dim3(NSEQ / 2), dim3(512), 0, stream>>>(
        raw, in_proj_w, conv_w, conv_b, x_proj_w, dt_proj_w, dt_proj_b,
        A_log, D_skip, out_proj_w, proj_w, proj_b, (float*)d_out);
}